// Round 5
// baseline (7902.010 us; speedup 1.0000x reference)
//
#include <hip/hip_runtime.h>
#include <stdint.h>

#define B_  16
#define T_  2048
#define D_  512

typedef short v8s __attribute__((ext_vector_type(8)));
typedef float v4f __attribute__((ext_vector_type(4)));
typedef unsigned long long u64;
typedef u64 v2u __attribute__((ext_vector_type(2)));

#define POIS 0xAAAAAAAAAAAAAAAAull

// ws layout (bytes)
#define WT_OFF    0u           // 8 MB  bf16 weight fragments
#define H0_OFF    8388608u     // 32 MB h0 packed [t][d/8][b][8] bf16
#define H1_OFF    41943040u    // 32 MB h1 packed
#define FLAGS_OFF 75497472u    // 128 ints (flags0[64], flags1[64])
#define XB_OFF    75501568u    // 32 MB x packed [t][d/8][b][8] bf16 (optional)
#define WS_NEED_FULL (XB_OFF + 33554432u)

__device__ __forceinline__ short f2bf(float f) {
  unsigned u = __builtin_bit_cast(unsigned, f);
  u = (u + 0x7FFFu + ((u >> 16) & 1u)) >> 16;
  return (short)u;
}
__device__ __forceinline__ float sigmoid_fast(float z) { return 1.f / (1.f + __expf(-z)); }
__device__ __forceinline__ float tanh_fast(float z) {
  float e = __expf(2.f * z);
  return 1.f - 2.f / (e + 1.f);
}
__device__ __forceinline__ int cohLoad(const int* p) {
  return __hip_atomic_load((int*)p, __ATOMIC_RELAXED, __HIP_MEMORY_SCOPE_AGENT);
}
__device__ __forceinline__ void cohStore(int* p, int v) {
  __hip_atomic_store(p, v, __ATOMIC_RELAXED, __HIP_MEMORY_SCOPE_AGENT);
}
__device__ __forceinline__ u64 cohLoad64(const u64* p) {
  return __hip_atomic_load((u64*)p, __ATOMIC_RELAXED, __HIP_MEMORY_SCOPE_AGENT);
}

// Poll this lane's 16 A-fragment chunks (coherent LLC loads) until none is the
// 0xAA poison pattern; the loads double as the ready-probe (saves the
// drain->flag->poll->load round trips). Flag protocol is the rare fallback.
__device__ __forceinline__ void pollFrags(const short* base, int aOff,
                                          const int* flagArr, int lane, int need,
                                          v8s afr[16]) {
  const u64* p = (const u64*)(base + aOff);
  int spins = 0;
  for (;;) {
    u64 lo[16], hi[16];
#pragma unroll
    for (int kk = 0; kk < 16; ++kk) {
      lo[kk] = cohLoad64(p + (size_t)kk * 128);
      hi[kk] = cohLoad64(p + (size_t)kk * 128 + 1);
    }
    bool ok = true;
#pragma unroll
    for (int kk = 0; kk < 16; ++kk) ok &= (lo[kk] != POIS) & (hi[kk] != POIS);
    if (__ballot(ok) == ~0ull) {
#pragma unroll
      for (int kk = 0; kk < 16; ++kk) {
        v2u w; w[0] = lo[kk]; w[1] = hi[kk];
        afr[kk] = __builtin_bit_cast(v8s, w);
      }
      return;
    }
    if (++spins > 512) break;
    if (spins > 8) __builtin_amdgcn_s_sleep(1);
  }
  // fallback: flag wait (deadlock-free), then one coherent reload
  for (;;) {
    int f = cohLoad(&flagArr[lane]);
    if (__ballot(f >= need) == ~0ull) break;
    __builtin_amdgcn_s_sleep(1);
  }
#pragma unroll
  for (int kk = 0; kk < 16; ++kk) {
    v2u w;
    w[0] = cohLoad64(p + (size_t)kk * 128);
    w[1] = cohLoad64(p + (size_t)kk * 128 + 1);
    afr[kk] = __builtin_bit_cast(v8s, w);
  }
}

// Wx/Wh fp32 [L][512][2048] -> bf16 MFMA B-fragment order (validated R1-R4)
__global__ void prep_weights(const float* __restrict__ Wx, const float* __restrict__ Wh,
                             short* __restrict__ wT, int* __restrict__ flags) {
  int tid = blockIdx.x * 256 + threadIdx.x;            // [0, 2^22)
  if (blockIdx.x == 0 && threadIdx.x < 128) flags[threadIdx.x] = 0;
  int l   = tid >> 21;
  int mat = (tid >> 20) & 1;
  int rem = tid & ((1 << 20) - 1);
  int k   = rem >> 11;
  int col = rem & 2047;
  const float* src = mat ? Wh : Wx;
  float v = src[(l << 20) + (k << 11) + col];
  int q = col >> 9, r9 = col & 511, g = r9 >> 3, jj = r9 & 7;
  int c = q * 8 + jj, ntile = c >> 4, n = c & 15;
  int kap = k >> 5, k5 = k & 31, quad = k5 >> 3, j = k5 & 7;
  int lane = quad * 16 + n;
  int dst = ((((l * 2 + mat) * 64 + g) * 2 + ntile) * 16 + kap) * 512 + lane * 8 + j;
  wT[dst] = f2bf(v);
}

// x [b][t][d] fp32 -> packed xP[t][d/8][b][d%8] bf16 (A-fragment-native layout)
__global__ void prep_x(const float* __restrict__ x, short* __restrict__ xP) {
  int tid = blockIdx.x * 256 + threadIdx.x;            // [0, 2^24)
  int b = tid >> 20, r = tid & ((1 << 20) - 1), t = r >> 9, d = r & 511;
  xP[(size_t)t * 8192 + (d >> 3) * 128 + b * 8 + (d & 7)] = f2bf(x[tid]);
}

template <bool XBF16>
__global__ __launch_bounds__(256, 1) void lstm_persist(
    const float* __restrict__ x, const short* __restrict__ xP,
    const short* __restrict__ wT, const float* __restrict__ bias,
    short* h0, short* h1, int* flags, float* __restrict__ out) {
  const int wg   = blockIdx.x;
  const int l    = wg >> 6;       // layer 0 or 1
  const int g    = wg & 63;       // column group (8 h-cols)
  const int tid  = threadIdx.x;
  const int wave = tid >> 6;
  const int lane = tid & 63;
  const int mat  = wave >> 1;     // 0 = input kernel, 1 = recurrent
  const int ntile = wave & 1;
  const int n15  = lane & 15;
  const int quad = lane >> 4;

  __shared__ float LDSG[2][16][36];   // pad 36 -> 2-way max (free, m136)
  __shared__ short WLDS[4][16][512];  // 64 KB weight fragments

  int* flags0 = flags;
  int* flags1 = flags + 64;
  int* flagsOwn = l ? flags1 : flags0;
  short* hOwnP = l ? h1 : h0;

  // stage loop-invariant B fragments -> LDS (once)
  {
    const short* wb = wT + (size_t)((((l * 2 + mat) * 64 + g) * 2 + ntile) * 16) * 512;
#pragma unroll
    for (int kk = 0; kk < 16; ++kk)
      *(v8s*)&WLDS[wave][kk][lane * 8] = *(const v8s*)(wb + kk * 512 + lane * 8);
  }
  __syncthreads();

  // wave0 epilogue state: lane -> (batch bb, col pair jp): cols g*8+2jp, +1
  const int bb = lane >> 2, jp = lane & 3;
  float bq[4][2];
#pragma unroll
  for (int q = 0; q < 4; ++q) {
    bq[q][0] = bias[l * 2048 + q * 512 + g * 8 + 2 * jp];
    bq[q][1] = bias[l * 2048 + q * 512 + g * 8 + 2 * jp + 1];
  }
  float c0 = 0.f, c1 = 0.f;

  const int aOff = quad * 128 + n15 * 8;   // shorts, within a 8192-elem t-slice

  for (int t = 0; t < T_; ++t) {
    // ---- lazy flag publish: drain last step's h store concurrently with
    // other waves' data-polling, then bump the fallback flag ----
    if (wave == 0 && t > 0) {
      asm volatile("" ::: "memory");
      __builtin_amdgcn_s_waitcnt(0);
      asm volatile("" ::: "memory");
      cohStore(&flagsOwn[g], t);          // steps [0, t) fully published
    }

    // ---------- MFMA: 16-col tile of (A @ Wmat) ----------
    v4f acc0 = {0.f, 0.f, 0.f, 0.f};
    v4f acc1 = {0.f, 0.f, 0.f, 0.f};
    if (mat == 0) {
      if (l == 0) {
        if (XBF16) {
          const short* p = xP + (size_t)t * 8192 + aOff;
          v8s afr[16];
#pragma unroll
          for (int kk = 0; kk < 16; ++kk) afr[kk] = *(const v8s*)(p + kk * 512);
#pragma unroll
          for (int kk = 0; kk < 16; kk += 2) {
            acc0 = __builtin_amdgcn_mfma_f32_16x16x32_bf16(afr[kk],     *(const v8s*)&WLDS[wave][kk][lane * 8],     acc0, 0, 0, 0);
            acc1 = __builtin_amdgcn_mfma_f32_16x16x32_bf16(afr[kk + 1], *(const v8s*)&WLDS[wave][kk + 1][lane * 8], acc1, 0, 0, 0);
          }
        } else {
          const float* A = x + (size_t)(n15 * T_ + t) * D_ + quad * 8;
#pragma unroll
          for (int kk = 0; kk < 16; ++kk) {
            float4 f0 = *(const float4*)(A + kk * 32);
            float4 f1 = *(const float4*)(A + kk * 32 + 4);
            v8s a;
            a[0] = f2bf(f0.x); a[1] = f2bf(f0.y); a[2] = f2bf(f0.z); a[3] = f2bf(f0.w);
            a[4] = f2bf(f1.x); a[5] = f2bf(f1.y); a[6] = f2bf(f1.z); a[7] = f2bf(f1.w);
            acc0 = __builtin_amdgcn_mfma_f32_16x16x32_bf16(a, *(const v8s*)&WLDS[wave][kk][lane * 8], acc0, 0, 0, 0);
          }
        }
      } else {
        v8s afr[16];
        pollFrags(h0, (int)((size_t)t * 8192) + aOff, flags0, lane, t + 1, afr);
#pragma unroll
        for (int kk = 0; kk < 16; kk += 2) {
          acc0 = __builtin_amdgcn_mfma_f32_16x16x32_bf16(afr[kk],     *(const v8s*)&WLDS[wave][kk][lane * 8],     acc0, 0, 0, 0);
          acc1 = __builtin_amdgcn_mfma_f32_16x16x32_bf16(afr[kk + 1], *(const v8s*)&WLDS[wave][kk + 1][lane * 8], acc1, 0, 0, 0);
        }
      }
    } else if (t > 0) {
      v8s afr[16];
      pollFrags(hOwnP, (int)((size_t)(t - 1) * 8192) + aOff, flagsOwn, lane, t, afr);
#pragma unroll
      for (int kk = 0; kk < 16; kk += 2) {
        acc0 = __builtin_amdgcn_mfma_f32_16x16x32_bf16(afr[kk],     *(const v8s*)&WLDS[wave][kk][lane * 8],     acc0, 0, 0, 0);
        acc1 = __builtin_amdgcn_mfma_f32_16x16x32_bf16(afr[kk + 1], *(const v8s*)&WLDS[wave][kk + 1][lane * 8], acc1, 0, 0, 0);
      }
    }
    acc0 += acc1;
    {
      const int rb = quad * 4;
#pragma unroll
      for (int r = 0; r < 4; ++r)
        LDSG[mat][rb + r][ntile * 16 + n15] = acc0[r];
    }
    __syncthreads();

    // wave0 grabs its gate partials between the barriers (cheap)
    float2 s[4];
    if (wave == 0) {
#pragma unroll
      for (int q = 0; q < 4; ++q) {
        float2 a0 = *(const float2*)&LDSG[0][bb][q * 8 + 2 * jp];
        float2 a1 = *(const float2*)&LDSG[1][bb][q * 8 + 2 * jp];
        s[q].x = a0.x + a1.x + bq[q][0];
        s[q].y = a0.y + a1.y + bq[q][1];
      }
    }
    __syncthreads();   // LDSG reusable for next step

    if (wave == 0) {
      float i0 = sigmoid_fast(s[0].x), i1 = sigmoid_fast(s[0].y);
      float f0 = sigmoid_fast(s[1].x), f1 = sigmoid_fast(s[1].y);
      float g0 = tanh_fast(s[2].x),    g1 = tanh_fast(s[2].y);
      float o0 = sigmoid_fast(s[3].x), o1 = sigmoid_fast(s[3].y);
      c0 = f0 * c0 + i0 * g0;
      c1 = f1 * c1 + i1 * g1;
      float h0v = o0 * tanh_fast(c0);
      float h1v = o1 * tanh_fast(c1);
      unsigned pack = (unsigned)(unsigned short)f2bf(h0v) |
                      ((unsigned)(unsigned short)f2bf(h1v) << 16);
      // one coalesced 256B coherent store; consumers data-poll it directly
      cohStore((int*)hOwnP + (size_t)t * 4096 + g * 64 + bb * 4 + jp, (int)pack);
      if (l == 1) {   // residual output (not consumed by anyone; drains lazily)
        size_t xi = (size_t)bb * T_ * D_ + (size_t)t * D_ + g * 8 + 2 * jp;
        float2 xv = *(const float2*)(x + xi);
        float2 ov; ov.x = h0v + xv.x; ov.y = h1v + xv.y;
        *(float2*)(out + xi) = ov;
      }
    }
  }
  // final fallback flag so late flag-path consumers can't deadlock
  if (wave == 0) {
    asm volatile("" ::: "memory");
    __builtin_amdgcn_s_waitcnt(0);
    asm volatile("" ::: "memory");
    cohStore(&flagsOwn[g], T_);
  }
}

extern "C" void kernel_launch(void* const* d_in, const int* in_sizes, int n_in,
                              void* d_out, int out_size, void* d_ws, size_t ws_size,
                              hipStream_t stream) {
  const float* x    = (const float*)d_in[0];
  const float* Wx   = (const float*)d_in[1];
  const float* Wh   = (const float*)d_in[2];
  const float* bias = (const float*)d_in[3];
  float* out = (float*)d_out;

  char* ws   = (char*)d_ws;
  short* wT  = (short*)(ws + WT_OFF);
  short* h0  = (short*)(ws + H0_OFF);
  short* h1  = (short*)(ws + H1_OFF);
  int* flags = (int*)(ws + FLAGS_OFF);
  short* xP  = (short*)(ws + XB_OFF);

  const bool xbf16 = (ws_size >= (size_t)WS_NEED_FULL);

  hipLaunchKernelGGL(prep_weights, dim3(16384), dim3(256), 0, stream, Wx, Wh, wT, flags);
  if (xbf16) {
    hipLaunchKernelGGL(prep_x, dim3(65536), dim3(256), 0, stream, x, xP);
    hipLaunchKernelGGL((lstm_persist<true>), dim3(128), dim3(256), 0, stream,
                       x, xP, wT, bias, h0, h1, flags, out);
  } else {
    hipLaunchKernelGGL((lstm_persist<false>), dim3(128), dim3(256), 0, stream,
                       x, xP, wT, bias, h0, h1, flags, out);
  }
}